// Round 4
// baseline (707.755 us; speedup 1.0000x reference)
//
#include <hip/hip_runtime.h>
#include <stdint.h>

#define NN 32768            // nodes
#define HID 512
#define EM 131072           // mol edges
#define EP 196608           // pro edges
#define AS1 __attribute__((address_space(1)))
#define AS3 __attribute__((address_space(3)))

typedef _Float16 h8 __attribute__((ext_vector_type(8)));
typedef float f4 __attribute__((ext_vector_type(4)));
typedef float f8 __attribute__((ext_vector_type(8)));

__device__ __forceinline__ void gload_lds16(const _Float16* g, _Float16* l) {
    __builtin_amdgcn_global_load_lds((AS1 void*)(g), (AS3 void*)(l), 16, 0, 0);
}
__device__ __forceinline__ f8 c8(h8 v) { return __builtin_convertvector(v, f8); }

// ---------------- fused weight conversion: transpose+cast to interleaved [K/32][N][32] ----
// Layout: element (n, k) of B^T stored at dst[((k>>5)*N + n)*32 + (k&31)].
// An MFMA B-fragment read (16 consecutive n, 8 consecutive k at lq*8) is then one
// CONTIGUOUS 1KB burst per wave instead of 16 scattered 64B sectors.
struct ConvJobs {
    const float* src[12];
    _Float16* dst[12];
    int K[12], N[12], Kp[12];
    int blk0[13];   // cumulative 32x32-tile starts
};

__global__ void conv_all(ConvJobs j) {
    __shared__ float tile[32][33];
    int blk = blockIdx.x, job = 0;
    while (blk >= j.blk0[job + 1]) ++job;
    int t = blk - j.blk0[job];
    int Kp = j.Kp[job], N = j.N[job], K = j.K[job];
    int ktiles = Kp >> 5;
    int n0 = (t / ktiles) << 5, k0 = (t % ktiles) << 5;
    int tn = threadIdx.x & 31, tr = threadIdx.x >> 5;
    const float* src = j.src[job];
    #pragma unroll
    for (int p = 0; p < 4; ++p) {
        int k = k0 + tr + p * 8;
        tile[tr + p * 8][tn] = (k < K) ? src[(size_t)k * N + n0 + tn] : 0.f;
    }
    __syncthreads();
    _Float16* dst = j.dst[job];
    #pragma unroll
    for (int p = 0; p < 4; ++p) {
        int nl = tr + p * 8;
        dst[((size_t)(k0 >> 5) * N + n0 + nl) * 32 + tn] = (_Float16)tile[tn][nl];
    }
}

// pad+cast features fp32 [NN,F] -> fp16 [NN,128]; z selects branch (combined mode)
__global__ void pad_x2(const float* s0, const float* s1, int F0, int F1, _Float16* dstb) {
    int z = blockIdx.z;
    const float* src = z ? s1 : s0;
    int F = z ? F1 : F0;
    _Float16* dst = dstb + (size_t)z * NN * 128;
    int idx = blockIdx.x * 256 + threadIdx.x;
    int i = idx >> 7, jj = idx & 127;
    dst[idx] = (jj < F) ? (_Float16)src[(size_t)i * F + jj] : (_Float16)0.f;
}

// ---------------- CSR build (both branches, meta arrays are [2][...]) ----------------
__global__ void init_deg(int* deg) {
    deg[(size_t)blockIdx.z * NN + blockIdx.x * 256 + threadIdx.x] = 1;  // self loop
}

__global__ void count_edges2(const int* c0, int E0, const int* c1, int E1, int* deg) {
    int i = blockIdx.x * 256 + threadIdx.x;
    if (i < E0) atomicAdd(&deg[c0[i]], 1);
    else { i -= E0; if (i < E1) atomicAdd(&deg[NN + c1[i]], 1); }
}

// exclusive scan of (deg-1) + dis = rsqrt(deg); one block per branch (blockIdx.z)
__global__ void scan_offsets(const int* degb, int* offsb, int* curb, float* disb) {
    const int* deg = degb + blockIdx.z * NN;
    int* offs = offsb + blockIdx.z * (NN + 1);
    int* cur = curb + blockIdx.z * NN;
    float* dis = disb + blockIdx.z * NN;
    __shared__ int part[1024];
    int t = threadIdx.x, base = t * 32;
    int loc[32], sum = 0;
    for (int jj = 0; jj < 32; ++jj) {
        int d = deg[base + jj];
        dis[base + jj] = rsqrtf((float)d);
        loc[jj] = sum; sum += d - 1;
    }
    part[t] = sum;
    __syncthreads();
    for (int o = 1; o < 1024; o <<= 1) {
        int v = (t >= o) ? part[t - o] : 0;
        __syncthreads();
        part[t] += v;
        __syncthreads();
    }
    int pre = (t == 0) ? 0 : part[t - 1];
    for (int jj = 0; jj < 32; ++jj) { int x = pre + loc[jj]; offs[base + jj] = x; cur[base + jj] = x; }
    if (t == 1023) offs[NN] = part[1023];
}

// scatter packs (source row, dis[source row]) into one int2 stream: the gather's per-edge
// dependent chain loses the 4 random dis scalar loads.
__global__ void scatter2(const int* r0, const int* c0, int E0,
                         const int* r1, const int* c1, int E1,
                         int* cur, const float* dis, int2* s0, int2* s1) {
    int i = blockIdx.x * 256 + threadIdx.x;
    if (i < E0) {
        int r = r0[i];
        int p = atomicAdd(&cur[c0[i]], 1);
        int2 v; v.x = r; v.y = __float_as_int(dis[r]);
        s0[p] = v;
    } else {
        i -= E0;
        if (i < E1) {
            int r = r1[i];
            int p = atomicAdd(&cur[NN + c1[i]], 1);
            int2 v; v.x = r; v.y = __float_as_int(dis[NN + r]);
            s1[p] = v;
        }
    }
}

// ---------------- fused layer: 128-row tile as two pipelined 64-row halves --------------
// T0: gather H0. T1: gather H1 || GEMM H0. T2: GEMM H1 || epilogue H0.
// T3: epilogue H1 || copy H0. T4: copy H1.  Disjoint LDS buffers per phase pair ->
// barrier-free overlap of gather (memory pipes) with GEMM (MFMA) across the 16 waves.
#define ROWP 536
#define HROWS 64

struct LArgs {
    const _Float16* pin;
    const _Float16* h0;
    _Float16* pout;            // unused when woutT != null
    const float* dis;
    const int* offs;
    const int2* se0;
    const int2* se1;
    const _Float16* wT;        // interleaved layer weights, z-stride 3*512*512
    const _Float16* woutT;     // interleaved out-proj weights, z-stride 128*512
    const float* bo[2];
    _Float16* xc;              // [NN, 256]
    size_t bstr;
    int mzadd;
};

__global__ __launch_bounds__(1024, 4) void layer_fused(LArgs a) {
    extern __shared__ _Float16 lds[];   // bufA [64][ROWP] | bufB [64][ROWP]
    _Float16* bufA = lds;
    _Float16* bufB = lds + HROWS * ROWP;
    const int z = blockIdx.z, mz = z + a.mzadd;
    const _Float16* __restrict__ pin = a.pin + (size_t)z * a.bstr;
    const _Float16* __restrict__ h0 = a.h0 + (size_t)z * a.bstr;
    const _Float16* __restrict__ BT = a.wT + (size_t)z * (3 * 512 * 512);
    const float* __restrict__ dis = a.dis + mz * NN;
    const int* __restrict__ offs = a.offs + mz * (NN + 1);
    const int2* __restrict__ se = mz ? a.se1 : a.se0;
    const int tid = threadIdx.x, wave = tid >> 6, lane = tid & 63;
    const int row0 = blockIdx.x * 128;
    const int l15 = lane & 15, lq = lane >> 4;

    // ---- gather 4 rows/wave into buf (rows [rbase, rbase+64) of the block tile) ----
    auto gather4 = [&](_Float16* buf, int rbase) {
        for (int i = 0; i < 4; ++i) {
            const int rl = wave * 4 + i, row = row0 + rbase + rl;
            const int e0 = offs[row], e1 = offs[row + 1];
            f8 acg = {};
            for (int e = e0; e < e1; e += 4) {
                const int j1 = (e + 1 < e1) ? e + 1 : e;
                const int j2 = (e + 2 < e1) ? e + 2 : e;
                const int j3 = (e + 3 < e1) ? e + 3 : e;
                const float m1 = (e + 1 < e1) ? 1.f : 0.f;
                const float m2 = (e + 2 < e1) ? 1.f : 0.f;
                const float m3 = (e + 3 < e1) ? 1.f : 0.f;
                const int2 p0 = se[e], p1 = se[j1], p2 = se[j2], p3 = se[j3];
                const float s0 = __int_as_float(p0.y);
                const float s1 = __int_as_float(p1.y) * m1;
                const float s2 = __int_as_float(p2.y) * m2;
                const float s3 = __int_as_float(p3.y) * m3;
                h8 v0 = *(const h8*)&pin[(size_t)p0.x * 512 + lane * 8];
                h8 v1 = *(const h8*)&pin[(size_t)p1.x * 512 + lane * 8];
                h8 v2 = *(const h8*)&pin[(size_t)p2.x * 512 + lane * 8];
                h8 v3 = *(const h8*)&pin[(size_t)p3.x * 512 + lane * 8];
                acg += s0 * c8(v0) + s1 * c8(v1) + s2 * c8(v2) + s3 * c8(v3);
            }
            const float si = dis[row];
            h8 pv = *(const h8*)&pin[(size_t)row * 512 + lane * 8];
            h8 hv = *(const h8*)&h0[(size_t)row * 512 + lane * 8];
            f8 r = 0.8f * si * (acg + si * c8(pv)) + 0.2f * c8(hv);
            *(h8*)&buf[rl * ROWP + lane * 8] = __builtin_convertvector(r, h8);
        }
    };

    // ---- GEMM: 64 rows of buf x this wave's 32-col slice; acc[4][2] ----
    auto gemmh = [&](const _Float16* buf, f4 (&acc)[4][2]) {
        #pragma unroll
        for (int kt = 0; kt < 8; ++kt) {
            #pragma unroll
            for (int s = 0; s < 2; ++s) {
                const int koff = kt * 64 + s * 32 + lq * 8;
                h8 af[4], bf[2];
                #pragma unroll
                for (int rt = 0; rt < 4; ++rt)
                    af[rt] = *(const h8*)&buf[(rt * 16 + l15) * ROWP + koff];
                #pragma unroll
                for (int ct = 0; ct < 2; ++ct)
                    bf[ct] = *(const h8*)(BT + ((size_t)(kt * 2 + s) * 512
                                                + wave * 32 + ct * 16 + l15) * 32 + lq * 8);
                #pragma unroll
                for (int rt = 0; rt < 4; ++rt)
                    #pragma unroll
                    for (int ct = 0; ct < 2; ++ct)
                        acc[rt][ct] = __builtin_amdgcn_mfma_f32_16x16x32_f16(af[rt], bf[ct], acc[rt][ct], 0, 0, 0);
            }
        }
    };

    // ---- epilogue: relu(buf + buf@W) -> buf in place (wave's 32-col slice) ----
    auto epih = [&](_Float16* buf, f4 (&acc)[4][2]) {
        #pragma unroll
        for (int rt = 0; rt < 4; ++rt) {
            #pragma unroll
            for (int ct = 0; ct < 2; ++ct) {
                const int col = wave * 32 + ct * 16 + l15;
                #pragma unroll
                for (int r = 0; r < 4; ++r) {
                    const int rl = rt * 16 + lq * 4 + r;
                    float nv = fmaxf((float)buf[rl * ROWP + col] + acc[rt][ct][r], 0.f);
                    buf[rl * ROWP + col] = (_Float16)nv;
                }
            }
        }
    };

    // ---- coalesced copy + residual: pout = relu_part + pin, full 1KB rows ----
    auto copyh = [&](const _Float16* buf, int rbase, _Float16* pout) {
        #pragma unroll
        for (int i = 0; i < 4; ++i) {
            const int rl = wave * 4 + i, row = row0 + rbase + rl;
            h8 s = *(const h8*)&buf[rl * ROWP + lane * 8];
            h8 pr = *(const h8*)&pin[(size_t)row * 512 + lane * 8];
            f8 v = c8(s) + c8(pr);
            *(h8*)&pout[(size_t)row * 512 + lane * 8] = __builtin_convertvector(v, h8);
        }
    };

    f4 accA[4][2] = {}, accB[4][2] = {};

    gather4(bufA, 0);                      // T0
    __syncthreads();
    gather4(bufB, 64);                     // T1: gather H1 || GEMM H0 (cross-wave overlap)
    gemmh(bufA, accA);
    __syncthreads();
    gemmh(bufB, accB);                     // T2: GEMM H1 || epilogue H0
    epih(bufA, accA);
    __syncthreads();

    const bool fuse_out = (a.woutT != nullptr);
    if (!fuse_out) {
        _Float16* __restrict__ pout = a.pout + (size_t)z * a.bstr;
        epih(bufB, accB);                  // T3: epilogue H1 || copy H0
        copyh(bufA, 0, pout);
        __syncthreads();
        copyh(bufB, 64, pout);             // T4
        return;
    }

    // ---- last layer: finish epilogue, residual into LDS, fused out-projection ----
    epih(bufB, accB);
    __syncthreads();
    #pragma unroll
    for (int i = 0; i < 8; ++i) {          // residual, row-owned: 8 rows/wave
        const int rloc = wave * 8 + i;
        _Float16* buf = (rloc < 64) ? bufA : bufB;
        const int rl = rloc & 63, row = row0 + rloc;
        h8 s = *(const h8*)&buf[rl * ROWP + lane * 8];
        h8 pr = *(const h8*)&pin[(size_t)row * 512 + lane * 8];
        f8 v = c8(s) + c8(pr);
        *(h8*)&buf[rl * ROWP + lane * 8] = __builtin_convertvector(v, h8);
    }
    __syncthreads();

    const _Float16* __restrict__ WO = a.woutT + (size_t)z * (128 * 512);
    const float* __restrict__ bo = a.bo[mz];
    const int wm = wave & 1, wn = wave >> 1;
    const _Float16* bsel = wm ? bufB : bufA;
    f4 acc2[4] = {};                       // 4 row frags x 1 col frag (16 cols/wave)
    #pragma unroll
    for (int kt = 0; kt < 8; ++kt) {
        #pragma unroll
        for (int s = 0; s < 2; ++s) {
            const int koff = kt * 64 + s * 32 + lq * 8;
            h8 af[4];
            #pragma unroll
            for (int rt = 0; rt < 4; ++rt)
                af[rt] = *(const h8*)&bsel[(rt * 16 + l15) * ROWP + koff];
            h8 bf = *(const h8*)(WO + ((size_t)(kt * 2 + s) * 128 + wn * 16 + l15) * 32 + lq * 8);
            #pragma unroll
            for (int rt = 0; rt < 4; ++rt)
                acc2[rt] = __builtin_amdgcn_mfma_f32_16x16x32_f16(af[rt], bf, acc2[rt], 0, 0, 0);
        }
    }
    __syncthreads();   // out-proj reads of both buffers done before stash overwrites
    // stash results [128 rows][128 cols] at stride 136 halfs (16B-aligned rows)
    #pragma unroll
    for (int rt = 0; rt < 4; ++rt) {
        const int col = wn * 16 + l15;
        #pragma unroll
        for (int r = 0; r < 4; ++r) {
            const int rl = wm * 64 + rt * 16 + lq * 4 + r;
            lds[rl * 136 + col] = (_Float16)(acc2[rt][r] + bo[col]);
        }
    }
    __syncthreads();
    // coalesced xc copy: 4 rows per instr (16 lanes x h8 per row = 256B)
    #pragma unroll
    for (int i = 0; i < 2; ++i) {
        const int rl = wave * 8 + i * 4 + (lane >> 4);
        const int co = lane & 15;
        *(h8*)&a.xc[(size_t)(row0 + rl) * 256 + mz * 128 + co * 8] =
            *(const h8*)&lds[rl * 136 + co * 8];
    }
}

// ---------------- staged-A barrier-free GEMM (K<=256): C = relu(A@B^T + bias) ---------------
// BT is interleaved [K/32][N][32]; ldc == N for both uses.
struct GArgs {
    const _Float16* A[2];
    const _Float16* BT[2];
    const float* bias[2];
    _Float16* C[2];
    _Float16* C2[2];
};

template <int K>
__global__ __launch_bounds__(512, 4) void gemm_a1(GArgs g, int ldc) {
    constexpr int NK = K / 64;
    __shared__ _Float16 lA[NK * 8 * 128 * 8];
    const int z = blockIdx.z;
    const _Float16* __restrict__ A = g.A[z];
    const _Float16* __restrict__ BT = g.BT[z];
    const int tid = threadIdx.x, wave = tid >> 6, lane = tid & 63;
    const int row0 = blockIdx.x * 128, col0 = blockIdx.y * 256;
    const int wm = wave & 1, wn = wave >> 1;          // 8 waves: 2 x 4, wave tile 64x64
    const int l15 = lane & 15, lq = lane >> 4;
    constexpr int CNT = NK * 16 / 8;                  // staging instrs per wave
    #pragma unroll
    for (int q = 0; q < CNT; ++q) {
        const int c = wave * CNT + q;
        const int kc = c >> 4, rem = c & 15, k8 = rem & 7, rh = rem >> 3;
        gload_lds16(A + (size_t)(row0 + rh * 64 + lane) * K + kc * 64 + k8 * 8,
                    &lA[((kc * 8 + k8) * 128 + rh * 64) * 8]);
    }
    __syncthreads();
    f4 acc[4][4] = {};
    #pragma unroll
    for (int kt = 0; kt < NK; ++kt) {
        #pragma unroll
        for (int s = 0; s < 2; ++s) {
            const int kq = s * 4 + lq;
            h8 af[4], bf[4];
            #pragma unroll
            for (int rt = 0; rt < 4; ++rt)
                af[rt] = *(const h8*)&lA[((kt * 8 + kq) * 128 + wm * 64 + rt * 16 + l15) * 8];
            #pragma unroll
            for (int ct = 0; ct < 4; ++ct)
                bf[ct] = *(const h8*)(BT + ((size_t)(kt * 2 + s) * ldc
                                            + col0 + wn * 64 + ct * 16 + l15) * 32 + lq * 8);
            #pragma unroll
            for (int rt = 0; rt < 4; ++rt)
                #pragma unroll
                for (int ct = 0; ct < 4; ++ct)
                    acc[rt][ct] = __builtin_amdgcn_mfma_f32_16x16x32_f16(af[rt], bf[ct], acc[rt][ct], 0, 0, 0);
        }
    }
    #pragma unroll
    for (int rt = 0; rt < 4; ++rt) {
        #pragma unroll
        for (int ct = 0; ct < 4; ++ct) {
            const int col = col0 + wn * 64 + ct * 16 + l15;
            #pragma unroll
            for (int r = 0; r < 4; ++r) {
                const int row = row0 + wm * 64 + rt * 16 + lq * 4 + r;
                float v = fmaxf(acc[rt][ct][r] + g.bias[z][col], 0.f);
                g.C[z][(size_t)row * ldc + col] = (_Float16)v;
                if (g.C2[z]) g.C2[z][(size_t)row * ldc + col] = (_Float16)v;
            }
        }
    }
}

// ---------------- fc2 + final dot: 1024 threads (16 waves, 4/SIMD), interleaved B ------
__global__ __launch_bounds__(1024, 4) void gemm_fc2f(
    const _Float16* __restrict__ A, const _Float16* __restrict__ BT,
    const float* __restrict__ b2, const float* __restrict__ wo,
    const float* __restrict__ bo, float* __restrict__ out) {
    extern __shared__ _Float16 lA[];                  // [128 k-octs][64 rows][8] + part[64][8]
    float* part = (float*)(lA + 64 * 1024);
    const int tid = threadIdx.x, wave = tid >> 6, lane = tid & 63;
    const int row0 = blockIdx.x * 64;
    const int wm = wave & 1, wn = wave >> 1;          // 16 waves: 2 x 8; wave tile 32x64
    const int l15 = lane & 15, lq = lane >> 4;
    #pragma unroll
    for (int q = 0; q < 8; ++q) {
        const int c = wave * 8 + q;                   // k-oct index
        gload_lds16(A + (size_t)(row0 + lane) * 1024 + c * 8, &lA[(c * 64) * 8]);
    }
    __syncthreads();
    f4 acc[2][4] = {};
    #pragma unroll
    for (int kt = 0; kt < 32; ++kt) {                 // K = 1024, 32-wide steps
        const int ko = kt * 4 + lq;
        h8 af[2], bf[4];
        #pragma unroll
        for (int rt = 0; rt < 2; ++rt)
            af[rt] = *(const h8*)&lA[(ko * 64 + wm * 32 + rt * 16 + l15) * 8];
        #pragma unroll
        for (int ct = 0; ct < 4; ++ct)
            bf[ct] = *(const h8*)(BT + ((size_t)kt * 512 + wn * 64 + ct * 16 + l15) * 32 + lq * 8);
        #pragma unroll
        for (int rt = 0; rt < 2; ++rt)
            #pragma unroll
            for (int ct = 0; ct < 4; ++ct)
                acc[rt][ct] = __builtin_amdgcn_mfma_f32_16x16x32_f16(af[rt], bf[ct], acc[rt][ct], 0, 0, 0);
    }
    #pragma unroll
    for (int rt = 0; rt < 2; ++rt) {
        #pragma unroll
        for (int r = 0; r < 4; ++r) {
            float p = 0.f;
            #pragma unroll
            for (int ct = 0; ct < 4; ++ct) {
                const int colg = wn * 64 + ct * 16 + l15;
                float v = fmaxf(acc[rt][ct][r] + b2[colg], 0.f);
                p += v * wo[colg];
            }
            p += __shfl_xor(p, 1); p += __shfl_xor(p, 2);
            p += __shfl_xor(p, 4); p += __shfl_xor(p, 8);
            if (l15 == 0) {
                const int rl = wm * 32 + rt * 16 + lq * 4 + r;
                part[rl * 8 + wn] = p;
            }
        }
    }
    __syncthreads();
    if (tid < 64) {
        float s = bo[0];
        #pragma unroll
        for (int q = 0; q < 8; ++q) s += part[tid * 8 + q];
        out[row0 + tid] = s;
    }
}

// ---------------- workspace plan ----------------
struct WS {
    int *deg, *offs, *cur;
    int2 *srow0, *srow1;
    float* dis;
    _Float16 *winT, *wsT, *woutT, *fc1T, *fc2T;
    _Float16 *xpad, *h0, *prev0, *prev1, *xc;
    size_t total;
};

static WS plan(char* base, bool comb) {
    size_t off = 0;
    auto al = [&](size_t n) { off = (off + 255) & ~(size_t)255; size_t o = off; off += n; return base + o; };
    WS w;
    w.deg   = (int*)al(2 * NN * 4);
    w.dis   = (float*)al(2 * NN * 4);
    w.offs  = (int*)al(2 * (NN + 1) * 4);
    w.cur   = (int*)al(2 * NN * 4);
    w.srow0 = (int2*)al((size_t)EM * 8);
    w.srow1 = (int2*)al((size_t)EP * 8);
    w.winT  = (_Float16*)al(2 * 512 * 128 * 2);
    w.wsT   = (_Float16*)al((size_t)2 * 3 * 512 * 512 * 2);
    w.woutT = (_Float16*)al(2 * 128 * 512 * 2);
    w.fc1T  = (_Float16*)al(1024 * 256 * 2);
    w.fc2T  = (_Float16*)al((size_t)512 * 1024 * 2);
    const size_t nb = comb ? 2 : 1;
    const size_t HB = (size_t)NN * HID * 2;      // 32 MB, 256-aligned -> h0/prev0 contiguous
    w.xpad  = (_Float16*)al(nb * NN * 128 * 2);
    w.h0    = (_Float16*)al(nb * HB);            // reused as x1 [NN,1024] in the head
    w.prev0 = (_Float16*)al(nb * HB);
    w.prev1 = (_Float16*)al(nb * HB);
    w.xc    = (_Float16*)al((size_t)NN * 256 * 2);
    w.total = off;
    return w;
}

// ---------------- host orchestration ----------------
extern "C" void kernel_launch(void* const* d_in, const int* in_sizes, int n_in,
                              void* d_out, int out_size, void* d_ws, size_t ws_size,
                              hipStream_t stream) {
    const float* mol_x   = (const float*)d_in[0];
    const int*   mol_ei  = (const int*)d_in[1];
    const float* pro_x   = (const float*)d_in[2];
    const int*   pro_ei  = (const int*)d_in[3];
    const float* win[2]  = {(const float*)d_in[4], (const float*)d_in[9]};
    const float* bin[2]  = {(const float*)d_in[5], (const float*)d_in[10]};
    const float* ws3[2]  = {(const float*)d_in[6], (const float*)d_in[11]};
    const float* wo[2]   = {(const float*)d_in[7], (const float*)d_in[12]};
    const float* bo[2]   = {(const float*)d_in[8], (const float*)d_in[13]};
    const float* w_fc1   = (const float*)d_in[14];
    const float* b_fc1   = (const float*)d_in[15];
    const float* w_fc2   = (const float*)d_in[16];
    const float* b_fc2   = (const float*)d_in[17];
    const float* w_o     = (const float*)d_in[18];
    const float* b_o     = (const float*)d_in[19];
    const int F[2] = {78, 54};

    char* wsb = (char*)d_ws;
    WS w = plan(wsb, true);
    const bool comb = (w.total <= ws_size);
    if (!comb) w = plan(wsb, false);
    const size_t BSTR = comb ? (size_t)NN * HID : 0;
    const size_t XSTR = comb ? (size_t)NN * 128 : 0;
    const int LDSB = 128 * ROWP * 2;                // 137216 B dynamic LDS (1 block/CU)
    const int LDSF = 64 * 1024 * 2 + 64 * 8 * 4;    // fc2f A-slab + part[64][8]

    hipFuncSetAttribute((const void*)layer_fused,
                        hipFuncAttributeMaxDynamicSharedMemorySize, LDSB);
    hipFuncSetAttribute((const void*)gemm_fc2f,
                        hipFuncAttributeMaxDynamicSharedMemorySize, LDSF);

    // --- 1. weight conversions (12 jobs, one launch, 32x32 tiles, interleaved layout) ---
    ConvJobs j;
    int nblk = 0, ji = 0;
    auto addjob = [&](const float* s, _Float16* d, int K, int N, int Kp) {
        j.src[ji] = s; j.dst[ji] = d; j.K[ji] = K; j.N[ji] = N; j.Kp[ji] = Kp;
        j.blk0[ji] = nblk; nblk += (N >> 5) * (Kp >> 5); ++ji;
    };
    for (int b = 0; b < 2; ++b) addjob(win[b], w.winT + b * 512 * 128, F[b], 512, 128);
    for (int b = 0; b < 2; ++b)
        for (int l = 0; l < 3; ++l)
            addjob(ws3[b] + (size_t)l * 512 * 512,
                   w.wsT + ((size_t)b * 3 + l) * 512 * 512, 512, 512, 512);
    for (int b = 0; b < 2; ++b) addjob(wo[b], w.woutT + b * 128 * 512, 512, 128, 512);
    addjob(w_fc1, w.fc1T, 256, 1024, 256);
    addjob(w_fc2, w.fc2T, 1024, 512, 1024);
    j.blk0[12] = nblk;
    conv_all<<<nblk, 256, 0, stream>>>(j);

    // --- 2. CSR build ---
    init_deg<<<dim3(NN / 256, 1, 2), 256, 0, stream>>>(w.deg);
    count_edges2<<<(EM + EP + 255) / 256, 256, 0, stream>>>(mol_ei + EM, EM, pro_ei + EP, EP, w.deg);
    scan_offsets<<<dim3(1, 1, 2), 1024, 0, stream>>>(w.deg, w.offs, w.cur, w.dis);
    scatter2<<<(EM + EP + 255) / 256, 256, 0, stream>>>(mol_ei, mol_ei + EM, EM,
                                                        pro_ei, pro_ei + EP, EP,
                                                        w.cur, w.dis, w.srow0, w.srow1);

    // --- 3. branches: input GEMM (writes h0 only; layer 0 reads pin = h0 directly) ---
    auto branch_chain = [&](int zcount, int b0) {
        GArgs g{};
        for (int z = 0; z < zcount; ++z) {
            int b = b0 + z;
            g.A[z] = w.xpad + z * XSTR;
            g.BT[z] = w.winT + b * 512 * 128;
            g.bias[z] = bin[b];
            g.C[z] = w.h0 + z * BSTR;
            g.C2[z] = nullptr;                    // prev == h0 at layer 0
        }
        gemm_a1<128><<<dim3(256, 2, zcount), 512, 0, stream>>>(g, HID);
        // ping-pong: l0: h0 -> prev1; l1: prev1 -> prev0; l2: prev0 -> (fused out-proj)
        const _Float16* pins[3] = {w.h0, w.prev1, w.prev0};
        _Float16* pouts[3] = {w.prev1, w.prev0, nullptr};
        for (int l = 0; l < 3; ++l) {
            LArgs a{};
            a.pin = pins[l];
            a.h0 = w.h0;
            a.pout = pouts[l];
            a.dis = w.dis; a.offs = w.offs;
            a.se0 = w.srow0; a.se1 = w.srow1;
            a.wT = w.wsT + ((size_t)b0 * 3 + l) * 512 * 512;
            a.woutT = (l == 2) ? (w.woutT + (size_t)b0 * 128 * 512) : nullptr;
            a.bo[0] = bo[0]; a.bo[1] = bo[1];
            a.xc = w.xc;
            a.bstr = BSTR; a.mzadd = b0;
            layer_fused<<<dim3(256, 1, zcount), 1024, LDSB, stream>>>(a);
        }
    };

    if (comb) {
        pad_x2<<<dim3(NN * 128 / 256, 1, 2), 256, 0, stream>>>(mol_x, pro_x, F[0], F[1], w.xpad);
        branch_chain(2, 0);
    } else {
        for (int b = 0; b < 2; ++b) {
            pad_x2<<<dim3(NN * 128 / 256, 1, 1), 256, 0, stream>>>(
                b ? pro_x : mol_x, nullptr, F[b], 0, w.xpad);
            branch_chain(1, b);
        }
    }

    // --- 4. MLP head: x1 = relu(xc@fc1+b1); out = relu(x1@fc2+b2).w_o + b_o (fused) ---
    _Float16* x1 = w.h0;    // [NN,1024]: comb -> h0 block (64MB); fallback -> h0+prev0 contiguous
    GArgs g1{};
    g1.A[0] = w.xc; g1.BT[0] = w.fc1T; g1.bias[0] = b_fc1; g1.C[0] = x1; g1.C2[0] = nullptr;
    gemm_a1<256><<<dim3(256, 4, 1), 512, 0, stream>>>(g1, 1024);
    gemm_fc2f<<<dim3(NN / 64, 1), 1024, LDSF, stream>>>(x1, w.fc2T, b_fc2, w_o, b_o, (float*)d_out);
    (void)in_sizes; (void)n_in; (void)out_size; (void)ws_size;
}

// Round 5
// 672.652 us; speedup vs baseline: 1.0522x; 1.0522x over previous
//
#include <hip/hip_runtime.h>
#include <stdint.h>

#define NN 32768            // nodes
#define HID 512
#define EM 131072           // mol edges
#define EP 196608           // pro edges
#define AS1 __attribute__((address_space(1)))
#define AS3 __attribute__((address_space(3)))

typedef _Float16 h8 __attribute__((ext_vector_type(8)));
typedef float f4 __attribute__((ext_vector_type(4)));
typedef float f8 __attribute__((ext_vector_type(8)));

__device__ __forceinline__ void gload_lds16(const _Float16* g, _Float16* l) {
    __builtin_amdgcn_global_load_lds((AS1 void*)(g), (AS3 void*)(l), 16, 0, 0);
}
__device__ __forceinline__ f8 c8(h8 v) { return __builtin_convertvector(v, f8); }

// ---------------- fused weight conversion: transpose+cast to interleaved [K/32][N][32] ----
// Layout: element (n, k) of B^T stored at dst[((k>>5)*N + n)*32 + (k&31)].
// An MFMA B-fragment read (16 consecutive n, 8 consecutive k at lq*8) is then one
// CONTIGUOUS 1KB burst per wave instead of 16 scattered 64B sectors.
struct ConvJobs {
    const float* src[12];
    _Float16* dst[12];
    int K[12], N[12], Kp[12];
    int blk0[13];   // cumulative 32x32-tile starts
};

__global__ void conv_all(ConvJobs j) {
    __shared__ float tile[32][33];
    int blk = blockIdx.x, job = 0;
    while (blk >= j.blk0[job + 1]) ++job;
    int t = blk - j.blk0[job];
    int Kp = j.Kp[job], N = j.N[job], K = j.K[job];
    int ktiles = Kp >> 5;
    int n0 = (t / ktiles) << 5, k0 = (t % ktiles) << 5;
    int tn = threadIdx.x & 31, tr = threadIdx.x >> 5;
    const float* src = j.src[job];
    #pragma unroll
    for (int p = 0; p < 4; ++p) {
        int k = k0 + tr + p * 8;
        tile[tr + p * 8][tn] = (k < K) ? src[(size_t)k * N + n0 + tn] : 0.f;
    }
    __syncthreads();
    _Float16* dst = j.dst[job];
    #pragma unroll
    for (int p = 0; p < 4; ++p) {
        int nl = tr + p * 8;
        dst[((size_t)(k0 >> 5) * N + n0 + nl) * 32 + tn] = (_Float16)tile[tn][nl];
    }
}

// pad+cast features fp32 [NN,F] -> fp16 [NN,128]; z selects branch (combined mode)
__global__ void pad_x2(const float* s0, const float* s1, int F0, int F1, _Float16* dstb) {
    int z = blockIdx.z;
    const float* src = z ? s1 : s0;
    int F = z ? F1 : F0;
    _Float16* dst = dstb + (size_t)z * NN * 128;
    int idx = blockIdx.x * 256 + threadIdx.x;
    int i = idx >> 7, jj = idx & 127;
    dst[idx] = (jj < F) ? (_Float16)src[(size_t)i * F + jj] : (_Float16)0.f;
}

// ---------------- CSR build (both branches, meta arrays are [2][...]) ----------------
__global__ void init_deg(int* deg) {
    deg[(size_t)blockIdx.z * NN + blockIdx.x * 256 + threadIdx.x] = 1;  // self loop
}

__global__ void count_edges2(const int* c0, int E0, const int* c1, int E1, int* deg) {
    int i = blockIdx.x * 256 + threadIdx.x;
    if (i < E0) atomicAdd(&deg[c0[i]], 1);
    else { i -= E0; if (i < E1) atomicAdd(&deg[NN + c1[i]], 1); }
}

// exclusive scan of (deg-1) + dis = rsqrt(deg); one block per branch (blockIdx.z)
__global__ void scan_offsets(const int* degb, int* offsb, int* curb, float* disb) {
    const int* deg = degb + blockIdx.z * NN;
    int* offs = offsb + blockIdx.z * (NN + 1);
    int* cur = curb + blockIdx.z * NN;
    float* dis = disb + blockIdx.z * NN;
    __shared__ int part[1024];
    int t = threadIdx.x, base = t * 32;
    int loc[32], sum = 0;
    for (int jj = 0; jj < 32; ++jj) {
        int d = deg[base + jj];
        dis[base + jj] = rsqrtf((float)d);
        loc[jj] = sum; sum += d - 1;
    }
    part[t] = sum;
    __syncthreads();
    for (int o = 1; o < 1024; o <<= 1) {
        int v = (t >= o) ? part[t - o] : 0;
        __syncthreads();
        part[t] += v;
        __syncthreads();
    }
    int pre = (t == 0) ? 0 : part[t - 1];
    for (int jj = 0; jj < 32; ++jj) { int x = pre + loc[jj]; offs[base + jj] = x; cur[base + jj] = x; }
    if (t == 1023) offs[NN] = part[1023];
}

// scatter packs (source row, dis[source row]) into one int2 stream: the gather's per-edge
// dependent chain loses the 4 random dis scalar loads.
__global__ void scatter2(const int* r0, const int* c0, int E0,
                         const int* r1, const int* c1, int E1,
                         int* cur, const float* dis, int2* s0, int2* s1) {
    int i = blockIdx.x * 256 + threadIdx.x;
    if (i < E0) {
        int r = r0[i];
        int p = atomicAdd(&cur[c0[i]], 1);
        int2 v; v.x = r; v.y = __float_as_int(dis[r]);
        s0[p] = v;
    } else {
        i -= E0;
        if (i < E1) {
            int r = r1[i];
            int p = atomicAdd(&cur[NN + c1[i]], 1);
            int2 v; v.x = r; v.y = __float_as_int(dis[NN + r]);
            s1[p] = v;
        }
    }
}

// ---------------- fused layer: 128-row tile, 1024 threads (round-2 proven config) ------
// Phase 1: 16 waves gather 8 rows each into LDS (packed int2 edge stream).
// Phase 2: barrier-free GEMM, B-fragments as 1KB bursts from interleaved wsT.
// Epilogue: relu(sup + sup@W) in place; residual (+pin) applied during the coalesced
// row copy (h8 reads) instead of 2B column scatters.
#define ROWP 536

struct LArgs {
    const _Float16* pin;
    const _Float16* h0;
    _Float16* pout;            // unused when woutT != null
    const float* dis;
    const int* offs;
    const int2* se0;
    const int2* se1;
    const _Float16* wT;        // interleaved layer weights, z-stride 3*512*512
    const _Float16* woutT;     // interleaved out-proj weights, z-stride 128*512
    const float* bo[2];
    _Float16* xc;              // [NN, 256]
    size_t bstr;
    int mzadd;
};

__global__ __launch_bounds__(1024, 4) void layer_fused(LArgs a) {
    extern __shared__ _Float16 sup[];   // [128][ROWP]
    const int z = blockIdx.z, mz = z + a.mzadd;
    const _Float16* __restrict__ pin = a.pin + (size_t)z * a.bstr;
    const _Float16* __restrict__ h0 = a.h0 + (size_t)z * a.bstr;
    const _Float16* __restrict__ BT = a.wT + (size_t)z * (3 * 512 * 512);
    const float* __restrict__ dis = a.dis + mz * NN;
    const int* __restrict__ offs = a.offs + mz * (NN + 1);
    const int2* __restrict__ se = mz ? a.se1 : a.se0;
    const int tid = threadIdx.x, wave = tid >> 6, lane = tid & 63;
    const int row0 = blockIdx.x * 128;

    // ---- phase 1: gather 8 rows per wave; 4-wide independent-load batches ----
    for (int i = 0; i < 8; ++i) {
        const int rl = wave * 8 + i, row = row0 + rl;
        const int e0 = offs[row], e1 = offs[row + 1];
        f8 acg = {};
        for (int e = e0; e < e1; e += 4) {
            const int j1 = (e + 1 < e1) ? e + 1 : e;
            const int j2 = (e + 2 < e1) ? e + 2 : e;
            const int j3 = (e + 3 < e1) ? e + 3 : e;
            const float m1 = (e + 1 < e1) ? 1.f : 0.f;
            const float m2 = (e + 2 < e1) ? 1.f : 0.f;
            const float m3 = (e + 3 < e1) ? 1.f : 0.f;
            const int2 p0 = se[e], p1 = se[j1], p2 = se[j2], p3 = se[j3];
            const float s0 = __int_as_float(p0.y);
            const float s1 = __int_as_float(p1.y) * m1;
            const float s2 = __int_as_float(p2.y) * m2;
            const float s3 = __int_as_float(p3.y) * m3;
            h8 v0 = *(const h8*)&pin[(size_t)p0.x * 512 + lane * 8];
            h8 v1 = *(const h8*)&pin[(size_t)p1.x * 512 + lane * 8];
            h8 v2 = *(const h8*)&pin[(size_t)p2.x * 512 + lane * 8];
            h8 v3 = *(const h8*)&pin[(size_t)p3.x * 512 + lane * 8];
            acg += s0 * c8(v0) + s1 * c8(v1) + s2 * c8(v2) + s3 * c8(v3);
        }
        const float si = dis[row];
        h8 pv = *(const h8*)&pin[(size_t)row * 512 + lane * 8];
        h8 hv = *(const h8*)&h0[(size_t)row * 512 + lane * 8];
        f8 r = 0.8f * si * (acg + si * c8(pv)) + 0.2f * c8(hv);
        *(h8*)&sup[rl * ROWP + lane * 8] = __builtin_convertvector(r, h8);
    }
    __syncthreads();

    // ---- phase 2: barrier-free GEMM; 16 waves, wave tile 64x64 (4x4 frags) ----
    const int wm = wave & 1, wn = wave >> 1;          // wn in [0,8): 64-col slice
    const int l15 = lane & 15, lq = lane >> 4;
    f4 acc[4][4] = {};
    #pragma unroll
    for (int kt = 0; kt < 8; ++kt) {
        #pragma unroll
        for (int s = 0; s < 2; ++s) {
            const int koff = kt * 64 + s * 32 + lq * 8;
            h8 af[4], bf[4];
            #pragma unroll
            for (int rt = 0; rt < 4; ++rt)
                af[rt] = *(const h8*)&sup[(wm * 64 + rt * 16 + l15) * ROWP + koff];
            #pragma unroll
            for (int ct = 0; ct < 4; ++ct)
                bf[ct] = *(const h8*)(BT + ((size_t)(kt * 2 + s) * 512
                                            + wn * 64 + ct * 16 + l15) * 32 + lq * 8);
            #pragma unroll
            for (int rt = 0; rt < 4; ++rt)
                #pragma unroll
                for (int ct = 0; ct < 4; ++ct)
                    acc[rt][ct] = __builtin_amdgcn_mfma_f32_16x16x32_f16(af[rt], bf[ct], acc[rt][ct], 0, 0, 0);
        }
    }
    __syncthreads();   // all GEMM reads of sup complete before in-place overwrite

    // ---- epilogue: relu(sup + sup@W) -> sup (in place, own elements; residual later) ----
    #pragma unroll
    for (int rt = 0; rt < 4; ++rt) {
        #pragma unroll
        for (int ct = 0; ct < 4; ++ct) {
            const int col = wn * 64 + ct * 16 + l15;
            #pragma unroll
            for (int r = 0; r < 4; ++r) {
                const int rl = wm * 64 + rt * 16 + lq * 4 + r;
                float nv = fmaxf((float)sup[rl * ROWP + col] + acc[rt][ct][r], 0.f);
                sup[rl * ROWP + col] = (_Float16)nv;
            }
        }
    }
    __syncthreads();

    const bool fuse_out = (a.woutT != nullptr);
    if (!fuse_out) {
        // ---- coalesced copy + residual: pout = relu_part + pin, full 1KB rows ----
        _Float16* __restrict__ pout = a.pout + (size_t)z * a.bstr;
        #pragma unroll
        for (int i = 0; i < 8; ++i) {
            const int rl = wave * 8 + i, row = row0 + rl;
            h8 s = *(const h8*)&sup[rl * ROWP + lane * 8];
            h8 pr = *(const h8*)&pin[(size_t)row * 512 + lane * 8];
            f8 v = c8(s) + c8(pr);
            *(h8*)&pout[(size_t)row * 512 + lane * 8] = __builtin_convertvector(v, h8);
        }
        return;
    }

    // ---- last layer: residual into LDS (coalesced), then fused out-projection ----
    #pragma unroll
    for (int i = 0; i < 8; ++i) {
        const int rl = wave * 8 + i, row = row0 + rl;
        h8 s = *(const h8*)&sup[rl * ROWP + lane * 8];
        h8 pr = *(const h8*)&pin[(size_t)row * 512 + lane * 8];
        f8 v = c8(s) + c8(pr);
        *(h8*)&sup[rl * ROWP + lane * 8] = __builtin_convertvector(v, h8);
    }
    __syncthreads();

    const _Float16* __restrict__ WO = a.woutT + (size_t)z * (128 * 512);
    const float* __restrict__ bo = a.bo[mz];
    f4 acc2[4] = {};                                  // 4 row frags x 1 col frag (16 cols/wave)
    #pragma unroll
    for (int kt = 0; kt < 8; ++kt) {
        #pragma unroll
        for (int s = 0; s < 2; ++s) {
            const int koff = kt * 64 + s * 32 + lq * 8;
            h8 af[4];
            #pragma unroll
            for (int rt = 0; rt < 4; ++rt)
                af[rt] = *(const h8*)&sup[(wm * 64 + rt * 16 + l15) * ROWP + koff];
            h8 bf = *(const h8*)(WO + ((size_t)(kt * 2 + s) * 128 + wn * 16 + l15) * 32 + lq * 8);
            #pragma unroll
            for (int rt = 0; rt < 4; ++rt)
                acc2[rt] = __builtin_amdgcn_mfma_f32_16x16x32_f16(af[rt], bf, acc2[rt], 0, 0, 0);
        }
    }
    __syncthreads();   // out-proj reads of sup done before stash overwrites
    // stash results [128 rows][128 cols] at stride 136 halfs (16B-aligned rows)
    #pragma unroll
    for (int rt = 0; rt < 4; ++rt) {
        const int col = wn * 16 + l15;
        #pragma unroll
        for (int r = 0; r < 4; ++r) {
            const int rl = wm * 64 + rt * 16 + lq * 4 + r;
            sup[rl * 136 + col] = (_Float16)(acc2[rt][r] + bo[col]);
        }
    }
    __syncthreads();
    // coalesced xc copy: 4 rows per instr (16 lanes x h8 per row = 256B)
    #pragma unroll
    for (int i = 0; i < 2; ++i) {
        const int rl = wave * 8 + i * 4 + (lane >> 4);
        const int co = lane & 15;
        *(h8*)&a.xc[(size_t)(row0 + rl) * 256 + mz * 128 + co * 8] =
            *(const h8*)&sup[rl * 136 + co * 8];
    }
}

// ---------------- staged-A barrier-free GEMM (K<=256): C = relu(A@B^T + bias) ---------------
// BT is interleaved [K/32][N][32]; ldc == N.
struct GArgs {
    const _Float16* A[2];
    const _Float16* BT[2];
    const float* bias[2];
    _Float16* C[2];
    _Float16* C2[2];
};

template <int K>
__global__ __launch_bounds__(512, 4) void gemm_a1(GArgs g, int ldc) {
    constexpr int NK = K / 64;
    __shared__ _Float16 lA[NK * 8 * 128 * 8];
    const int z = blockIdx.z;
    const _Float16* __restrict__ A = g.A[z];
    const _Float16* __restrict__ BT = g.BT[z];
    const int tid = threadIdx.x, wave = tid >> 6, lane = tid & 63;
    const int row0 = blockIdx.x * 128, col0 = blockIdx.y * 256;
    const int wm = wave & 1, wn = wave >> 1;          // 8 waves: 2 x 4, wave tile 64x64
    const int l15 = lane & 15, lq = lane >> 4;
    constexpr int CNT = NK * 16 / 8;                  // staging instrs per wave
    #pragma unroll
    for (int q = 0; q < CNT; ++q) {
        const int c = wave * CNT + q;
        const int kc = c >> 4, rem = c & 15, k8 = rem & 7, rh = rem >> 3;
        gload_lds16(A + (size_t)(row0 + rh * 64 + lane) * K + kc * 64 + k8 * 8,
                    &lA[((kc * 8 + k8) * 128 + rh * 64) * 8]);
    }
    __syncthreads();
    f4 acc[4][4] = {};
    #pragma unroll
    for (int kt = 0; kt < NK; ++kt) {
        #pragma unroll
        for (int s = 0; s < 2; ++s) {
            const int kq = s * 4 + lq;
            h8 af[4], bf[4];
            #pragma unroll
            for (int rt = 0; rt < 4; ++rt)
                af[rt] = *(const h8*)&lA[((kt * 8 + kq) * 128 + wm * 64 + rt * 16 + l15) * 8];
            #pragma unroll
            for (int ct = 0; ct < 4; ++ct)
                bf[ct] = *(const h8*)(BT + ((size_t)(kt * 2 + s) * ldc
                                            + col0 + wn * 64 + ct * 16 + l15) * 32 + lq * 8);
            #pragma unroll
            for (int rt = 0; rt < 4; ++rt)
                #pragma unroll
                for (int ct = 0; ct < 4; ++ct)
                    acc[rt][ct] = __builtin_amdgcn_mfma_f32_16x16x32_f16(af[rt], bf[ct], acc[rt][ct], 0, 0, 0);
        }
    }
    #pragma unroll
    for (int rt = 0; rt < 4; ++rt) {
        #pragma unroll
        for (int ct = 0; ct < 4; ++ct) {
            const int col = col0 + wn * 64 + ct * 16 + l15;
            #pragma unroll
            for (int r = 0; r < 4; ++r) {
                const int row = row0 + wm * 64 + rt * 16 + lq * 4 + r;
                float v = fmaxf(acc[rt][ct][r] + g.bias[z][col], 0.f);
                g.C[z][(size_t)row * ldc + col] = (_Float16)v;
                if (g.C2[z]) g.C2[z][(size_t)row * ldc + col] = (_Float16)v;
            }
        }
    }
}

// ---------------- fused MLP head: out = (relu(relu(xc@W1+b1)@W2+b2)).wo + bo ----------
// 64-row block, 1024 threads. x1 never hits global: per 128-col chunk of fc1, compute
// x1-chunk in-register -> relu+bias -> small LDS A-format buffer -> accumulate into the
// persistent fc2 accumulator acc2 (64x512 per block). Kills the 64MB x1 round-trip and
// the separate fc1 kernel.
__global__ __launch_bounds__(1024, 4) void head_fused(
    const _Float16* __restrict__ xc, const _Float16* __restrict__ W1T,
    const float* __restrict__ b1, const _Float16* __restrict__ W2T,
    const float* __restrict__ b2, const float* __restrict__ wo,
    const float* __restrict__ bo, float* __restrict__ out) {
    __shared__ _Float16 lxc[32 * 64 * 8];   // xc slab, A-format [koct][row][8] (32KB)
    __shared__ _Float16 lx1[16 * 64 * 8];   // x1 chunk, A-format (16KB)
    __shared__ float part[64 * 8];
    const int tid = threadIdx.x, wave = tid >> 6, lane = tid & 63;
    const int row0 = blockIdx.x * 64;
    const int wm = wave & 1, wn = wave >> 1;          // 16 waves: 2 row x 8 col groups
    const int l15 = lane & 15, lq = lane >> 4;
    #pragma unroll
    for (int q = 0; q < 2; ++q) {
        const int c = wave * 2 + q;                   // k-oct index (K=256 -> 32 octs)
        gload_lds16(xc + (size_t)(row0 + lane) * 256 + c * 8, &lxc[(c * 64) * 8]);
    }
    __syncthreads();
    f4 acc2[2][4] = {};                               // 32 rows x 64 cols per wave
    for (int cc = 0; cc < 8; ++cc) {
        // fc1 chunk: x1[:, cc*128:+128] = relu(xc @ W1 + b1); wave tile 32x16
        f4 acc1[2] = {};
        #pragma unroll
        for (int kt = 0; kt < 4; ++kt) {
            #pragma unroll
            for (int s = 0; s < 2; ++s) {
                const int kq = s * 4 + lq;
                h8 af[2];
                #pragma unroll
                for (int rt = 0; rt < 2; ++rt)
                    af[rt] = *(const h8*)&lxc[((kt * 8 + kq) * 64 + wm * 32 + rt * 16 + l15) * 8];
                const int col = cc * 128 + wn * 16 + l15;
                h8 bf = *(const h8*)(W1T + ((size_t)(kt * 2 + s) * 1024 + col) * 32 + lq * 8);
                #pragma unroll
                for (int rt = 0; rt < 2; ++rt)
                    acc1[rt] = __builtin_amdgcn_mfma_f32_16x16x32_f16(af[rt], bf, acc1[rt], 0, 0, 0);
            }
        }
        __syncthreads();   // previous chunk's fc2 reads of lx1 complete
        {
            const int cl = wn * 16 + l15;             // col within chunk
            const float bb = b1[cc * 128 + cl];
            #pragma unroll
            for (int rt = 0; rt < 2; ++rt)
                #pragma unroll
                for (int r = 0; r < 4; ++r) {
                    const int row = wm * 32 + rt * 16 + lq * 4 + r;
                    lx1[((cl >> 3) * 64 + row) * 8 + (cl & 7)] =
                        (_Float16)fmaxf(acc1[rt][r] + bb, 0.f);
                }
        }
        __syncthreads();   // lx1 ready
        // fc2 partial: acc2 += x1c @ W2[cc*128:+128, :]; wave tile 32x64
        #pragma unroll
        for (int kt = 0; kt < 2; ++kt) {
            #pragma unroll
            for (int s = 0; s < 2; ++s) {
                const int kq = s * 4 + lq;
                h8 af[2], bf[4];
                #pragma unroll
                for (int rt = 0; rt < 2; ++rt)
                    af[rt] = *(const h8*)&lx1[((kt * 8 + kq) * 64 + wm * 32 + rt * 16 + l15) * 8];
                #pragma unroll
                for (int ct = 0; ct < 4; ++ct)
                    bf[ct] = *(const h8*)(W2T + ((size_t)(cc * 4 + kt * 2 + s) * 512
                                                 + wn * 64 + ct * 16 + l15) * 32 + lq * 8);
                #pragma unroll
                for (int rt = 0; rt < 2; ++rt)
                    #pragma unroll
                    for (int ct = 0; ct < 4; ++ct)
                        acc2[rt][ct] = __builtin_amdgcn_mfma_f32_16x16x32_f16(af[rt], bf[ct], acc2[rt][ct], 0, 0, 0);
            }
        }
    }
    // epilogue: out = relu(acc2 + b2) . wo + bo, deterministic LDS reduction
    #pragma unroll
    for (int rt = 0; rt < 2; ++rt) {
        #pragma unroll
        for (int r = 0; r < 4; ++r) {
            float p = 0.f;
            #pragma unroll
            for (int ct = 0; ct < 4; ++ct) {
                const int colg = wn * 64 + ct * 16 + l15;
                float v = fmaxf(acc2[rt][ct][r] + b2[colg], 0.f);
                p += v * wo[colg];
            }
            p += __shfl_xor(p, 1); p += __shfl_xor(p, 2);
            p += __shfl_xor(p, 4); p += __shfl_xor(p, 8);
            if (l15 == 0) {
                const int rl = wm * 32 + rt * 16 + lq * 4 + r;
                part[rl * 8 + wn] = p;
            }
        }
    }
    __syncthreads();
    if (tid < 64) {
        float s = bo[0];
        #pragma unroll
        for (int q = 0; q < 8; ++q) s += part[tid * 8 + q];
        out[row0 + tid] = s;
    }
}

// ---------------- workspace plan ----------------
struct WS {
    int *deg, *offs, *cur;
    int2 *srow0, *srow1;
    float* dis;
    _Float16 *winT, *wsT, *woutT, *fc1T, *fc2T;
    _Float16 *xpad, *h0, *prev0, *prev1, *xc;
    size_t total;
};

static WS plan(char* base, bool comb) {
    size_t off = 0;
    auto al = [&](size_t n) { off = (off + 255) & ~(size_t)255; size_t o = off; off += n; return base + o; };
    WS w;
    w.deg   = (int*)al(2 * NN * 4);
    w.dis   = (float*)al(2 * NN * 4);
    w.offs  = (int*)al(2 * (NN + 1) * 4);
    w.cur   = (int*)al(2 * NN * 4);
    w.srow0 = (int2*)al((size_t)EM * 8);
    w.srow1 = (int2*)al((size_t)EP * 8);
    w.winT  = (_Float16*)al(2 * 512 * 128 * 2);
    w.wsT   = (_Float16*)al((size_t)2 * 3 * 512 * 512 * 2);
    w.woutT = (_Float16*)al(2 * 128 * 512 * 2);
    w.fc1T  = (_Float16*)al(1024 * 256 * 2);
    w.fc2T  = (_Float16*)al((size_t)512 * 1024 * 2);
    const size_t nb = comb ? 2 : 1;
    const size_t HB = (size_t)NN * HID * 2;      // 32 MB, 256-aligned -> h0/prev0 contiguous
    w.xpad  = (_Float16*)al(nb * NN * 128 * 2);
    w.h0    = (_Float16*)al(nb * HB);
    w.prev0 = (_Float16*)al(nb * HB);
    w.prev1 = (_Float16*)al(nb * HB);
    w.xc    = (_Float16*)al((size_t)NN * 256 * 2);
    w.total = off;
    return w;
}

// ---------------- host orchestration ----------------
extern "C" void kernel_launch(void* const* d_in, const int* in_sizes, int n_in,
                              void* d_out, int out_size, void* d_ws, size_t ws_size,
                              hipStream_t stream) {
    const float* mol_x   = (const float*)d_in[0];
    const int*   mol_ei  = (const int*)d_in[1];
    const float* pro_x   = (const float*)d_in[2];
    const int*   pro_ei  = (const int*)d_in[3];
    const float* win[2]  = {(const float*)d_in[4], (const float*)d_in[9]};
    const float* bin[2]  = {(const float*)d_in[5], (const float*)d_in[10]};
    const float* ws3[2]  = {(const float*)d_in[6], (const float*)d_in[11]};
    const float* wo[2]   = {(const float*)d_in[7], (const float*)d_in[12]};
    const float* bo[2]   = {(const float*)d_in[8], (const float*)d_in[13]};
    const float* w_fc1   = (const float*)d_in[14];
    const float* b_fc1   = (const float*)d_in[15];
    const float* w_fc2   = (const float*)d_in[16];
    const float* b_fc2   = (const float*)d_in[17];
    const float* w_o     = (const float*)d_in[18];
    const float* b_o     = (const float*)d_in[19];
    const int F[2] = {78, 54};

    char* wsb = (char*)d_ws;
    WS w = plan(wsb, true);
    const bool comb = (w.total <= ws_size);
    if (!comb) w = plan(wsb, false);
    const size_t BSTR = comb ? (size_t)NN * HID : 0;
    const size_t XSTR = comb ? (size_t)NN * 128 : 0;
    const int LDSB = 128 * ROWP * 2;                // 137216 B dynamic LDS (1 block/CU)

    hipFuncSetAttribute((const void*)layer_fused,
                        hipFuncAttributeMaxDynamicSharedMemorySize, LDSB);

    // --- 1. weight conversions (12 jobs, one launch, 32x32 tiles, interleaved layout) ---
    ConvJobs j;
    int nblk = 0, ji = 0;
    auto addjob = [&](const float* s, _Float16* d, int K, int N, int Kp) {
        j.src[ji] = s; j.dst[ji] = d; j.K[ji] = K; j.N[ji] = N; j.Kp[ji] = Kp;
        j.blk0[ji] = nblk; nblk += (N >> 5) * (Kp >> 5); ++ji;
    };
    for (int b = 0; b < 2; ++b) addjob(win[b], w.winT + b * 512 * 128, F[b], 512, 128);
    for (int b = 0; b < 2; ++b)
        for (int l = 0; l < 3; ++l)
            addjob(ws3[b] + (size_t)l * 512 * 512,
                   w.wsT + ((size_t)b * 3 + l) * 512 * 512, 512, 512, 512);
    for (int b = 0; b < 2; ++b) addjob(wo[b], w.woutT + b * 128 * 512, 512, 128, 512);
    addjob(w_fc1, w.fc1T, 256, 1024, 256);
    addjob(w_fc2, w.fc2T, 1024, 512, 1024);
    j.blk0[12] = nblk;
    conv_all<<<nblk, 256, 0, stream>>>(j);

    // --- 2. CSR build ---
    init_deg<<<dim3(NN / 256, 1, 2), 256, 0, stream>>>(w.deg);
    count_edges2<<<(EM + EP + 255) / 256, 256, 0, stream>>>(mol_ei + EM, EM, pro_ei + EP, EP, w.deg);
    scan_offsets<<<dim3(1, 1, 2), 1024, 0, stream>>>(w.deg, w.offs, w.cur, w.dis);
    scatter2<<<(EM + EP + 255) / 256, 256, 0, stream>>>(mol_ei, mol_ei + EM, EM,
                                                        pro_ei, pro_ei + EP, EP,
                                                        w.cur, w.dis, w.srow0, w.srow1);

    // --- 3. branches: input GEMM (writes h0 only; layer 0 reads pin = h0 directly) ---
    auto branch_chain = [&](int zcount, int b0) {
        GArgs g{};
        for (int z = 0; z < zcount; ++z) {
            int b = b0 + z;
            g.A[z] = w.xpad + z * XSTR;
            g.BT[z] = w.winT + b * 512 * 128;
            g.bias[z] = bin[b];
            g.C[z] = w.h0 + z * BSTR;
            g.C2[z] = nullptr;                    // prev == h0 at layer 0
        }
        gemm_a1<128><<<dim3(256, 2, zcount), 512, 0, stream>>>(g, HID);
        // ping-pong: l0: h0 -> prev1; l1: prev1 -> prev0; l2: prev0 -> (fused out-proj)
        const _Float16* pins[3] = {w.h0, w.prev1, w.prev0};
        _Float16* pouts[3] = {w.prev1, w.prev0, nullptr};
        for (int l = 0; l < 3; ++l) {
            LArgs a{};
            a.pin = pins[l];
            a.h0 = w.h0;
            a.pout = pouts[l];
            a.dis = w.dis; a.offs = w.offs;
            a.se0 = w.srow0; a.se1 = w.srow1;
            a.wT = w.wsT + ((size_t)b0 * 3 + l) * 512 * 512;
            a.woutT = (l == 2) ? (w.woutT + (size_t)b0 * 128 * 512) : nullptr;
            a.bo[0] = bo[0]; a.bo[1] = bo[1];
            a.xc = w.xc;
            a.bstr = BSTR; a.mzadd = b0;
            layer_fused<<<dim3(256, 1, zcount), 1024, LDSB, stream>>>(a);
        }
    };

    if (comb) {
        pad_x2<<<dim3(NN * 128 / 256, 1, 2), 256, 0, stream>>>(mol_x, pro_x, F[0], F[1], w.xpad);
        branch_chain(2, 0);
    } else {
        for (int b = 0; b < 2; ++b) {
            pad_x2<<<dim3(NN * 128 / 256, 1, 1), 256, 0, stream>>>(
                b ? pro_x : mol_x, nullptr, F[b], 0, w.xpad);
            branch_chain(1, b);
        }
    }

    // --- 4. MLP head: fully fused (fc1 + fc2 + final dot), x1 stays on-chip ---
    head_fused<<<dim3(NN / 64, 1), 1024, 0, stream>>>(
        w.xc, w.fc1T, b_fc1, w.fc2T, b_fc2, w_o, b_o, (float*)d_out);
    (void)in_sizes; (void)n_in; (void)out_size; (void)ws_size;
}